// Round 7
// baseline (188.086 us; speedup 1.0000x reference)
//
#include <hip/hip_runtime.h>
#include <stdint.h>
#include <stddef.h>

// ---------------------------------------------------------------------------
// out = softmax(x Wq+bq @ (x Wk+bk)^T) * sqrt(512) @ (x Wv+bv)
// B=8, N=2048, D=DK=DV=512, fp32 I/O.
// Round 7: k_pv4 -- V goes global->register (each wave's disjoint 64-dv
// fragment loaded straight from Vt, L2-local); only P transits LDS,
// double-buffered, ONE lgkm-only barrier per iter; S prefetched 1 iter
// ahead in registers. conv/proj/qk unchanged.
// ws layout (B): x16 0, Q 16777216, K 33554432, Vt 50331648,
//   S 67108864 (134217728), Wt 201326592 (1572864), mEnc 202899456 (65536).
//   total 202964992.
// ---------------------------------------------------------------------------

typedef _Float16 f16_t;
typedef _Float16 f16x8 __attribute__((ext_vector_type(8)));
typedef float    f32x4 __attribute__((ext_vector_type(4)));

__device__ __forceinline__ f32x4 mfma_h(f16x8 a, f16x8 b, f32x4 c) {
  // D frag: col = lane&15, row = (lane>>4)*4 + reg
  return __builtin_amdgcn_mfma_f32_16x16x32_f16(a, b, c, 0, 0, 0);
}

__device__ __forceinline__ void gl_lds16(const void* g, void* lds) {
  __builtin_amdgcn_global_load_lds(
      (const __attribute__((address_space(1))) unsigned int*)g,
      (__attribute__((address_space(3))) unsigned int*)lds, 16, 0, 0);
}

// Stage a [128][64] f16 tile (16 KB) from row-major global via global_load_lds.
// Linear LDS dest; source pre-swizzled: phys slot s of row r holds logical
// slot s^(r&7) (16B slots, 8 per 128B row).  4-wave cooperative.
__device__ __forceinline__ void stage_tile(f16_t* lds, const f16_t* g,
                                           size_t gstride, int wave, int lane) {
  const int l8 = lane >> 3;
  const int lslot = (lane & 7) ^ l8;
  #pragma unroll
  for (int c = 0; c < 4; ++c) {
    const int chunk = wave * 4 + c;
    const int row = chunk * 8 + l8;
    gl_lds16(g + (size_t)row * gstride + lslot * 8, lds + chunk * 512);
  }
}

// Swizzled fragment read: logical (row R, 8 elems at col slot*8)
__device__ __forceinline__ f16x8 lds_frag(const f16_t* buf, int R, int slot) {
  return *(const f16x8*)&buf[R * 64 + (((slot ^ (R & 7)) & 7) << 3)];
}

// monotonic float<->uint encoding for atomicMax (memset-0 == -huge sentinel)
__device__ __forceinline__ unsigned int fenc(float f) {
  unsigned int u = __float_as_uint(f);
  return (u & 0x80000000u) ? ~u : (u | 0x80000000u);
}
__device__ __forceinline__ float fdec(unsigned int e) {
  unsigned int u = (e & 0x80000000u) ? (e & 0x7fffffffu) : ~e;
  return __uint_as_float(u);
}

// XCD-chunked work remap (requires nwg % 8 == 0)
__device__ __forceinline__ int xcd_swz(int id, int nwg) {
  return (id & 7) * (nwg >> 3) + (id >> 3);
}

// ---------------------------------------------------------------------------
__global__ __launch_bounds__(256) void k_conv_x(const float* __restrict__ x,
                                                f16_t* __restrict__ x16) {
  const int i = (blockIdx.x * 256 + threadIdx.x) * 8;
  const float4 a = *(const float4*)&x[i];
  const float4 b = *(const float4*)&x[i + 4];
  float v[8] = {a.x, a.y, a.z, a.w, b.x, b.y, b.z, b.w};
  f16x8 h;
  #pragma unroll
  for (int j = 0; j < 8; ++j) h[j] = (f16_t)v[j];
  *(f16x8*)&x16[i] = h;
}

// transpose+convert W -> Wt[p][n][k] f16
__global__ __launch_bounds__(256) void k_conv_w(const float* __restrict__ Wq,
                                                const float* __restrict__ Wk,
                                                const float* __restrict__ Wv,
                                                f16_t* __restrict__ Wt) {
  __shared__ float t[64][65];
  const int p = blockIdx.z;
  const float* __restrict__ W = (p == 0) ? Wq : (p == 1) ? Wk : Wv;
  const int n0 = blockIdx.x * 64, k0 = blockIdx.y * 64;
  const int tx = threadIdx.x & 63, ty = threadIdx.x >> 6;
  #pragma unroll
  for (int j = 0; j < 16; ++j)
    t[ty * 16 + j][tx] = W[(size_t)(k0 + ty * 16 + j) * 512 + n0 + tx];
  __syncthreads();
  #pragma unroll
  for (int j = 0; j < 16; ++j) {
    const int nl = ty * 16 + j;
    Wt[(size_t)p * 262144 + (size_t)(n0 + nl) * 512 + k0 + tx] =
        (f16_t)t[tx][nl];
  }
}

// ---------------------------------------------------------------------------
// Projection: flat grid 1536 (xcd-swizzled -> mt*12+jt).  Single fp16 MFMA.
// panels 0-3 Q, 4-7 K, 8-11 V (V transposed to Vt[b][dv][n]).
// ---------------------------------------------------------------------------
__global__ __launch_bounds__(256, 2) void k_proj(
    const f16_t* __restrict__ x16, const f16_t* __restrict__ Wt,
    const float* __restrict__ bq, const float* __restrict__ bk,
    const float* __restrict__ bv,
    f16_t* __restrict__ Q, f16_t* __restrict__ K, f16_t* __restrict__ Vt)
{
  __shared__ __align__(16) unsigned char smem[34816];  // A,B tiles / vtl
  f16_t* A = (f16_t*)smem;
  f16_t* B = (f16_t*)(smem + 16384);

  const int wg = xcd_swz(blockIdx.x, 1536);
  const int mt = wg / 12, jt = wg % 12;
  const int which = jt >> 2;            // 0=Q 1=K 2=V
  const int jb = (jt & 3) * 128;

  const int tid = threadIdx.x, lane = tid & 63, wave = tid >> 6;
  const int wr = wave >> 1, wc = wave & 1, l15 = lane & 15, lg = lane >> 4;
  const int rowbase = mt * 128;

  const f16_t* Wbase = Wt + (size_t)which * 262144 + (size_t)jb * 512;

  f32x4 acc[4][4] = {};

  for (int kb = 0; kb < 512; kb += 64) {
    __syncthreads();
    stage_tile(A, x16 + (size_t)rowbase * 512 + kb, 512, wave, lane);
    stage_tile(B, Wbase + kb, 512, wave, lane);
    __syncthreads();
    #pragma unroll
    for (int h = 0; h < 2; ++h) {
      const int slot0 = h * 4 + lg;
      f16x8 af[4], bf[4];
      #pragma unroll
      for (int g = 0; g < 4; ++g) {
        af[g] = lds_frag(A, wr * 64 + g * 16 + l15, slot0);
        bf[g] = lds_frag(B, wc * 64 + g * 16 + l15, slot0);
      }
      #pragma unroll
      for (int i = 0; i < 4; ++i)
        #pragma unroll
        for (int j = 0; j < 4; ++j)
          acc[i][j] = mfma_h(af[i], bf[j], acc[i][j]);
    }
  }

  if (which != 2) {
    f16_t* __restrict__ O = (which == 0) ? Q : K;
    const float* __restrict__ bb = (which == 0) ? bq : bk;
    #pragma unroll
    for (int j = 0; j < 4; ++j) {
      const int jl = jb + wc * 64 + j * 16 + l15;
      const float bias = bb[jl];
      #pragma unroll
      for (int i = 0; i < 4; ++i)
        #pragma unroll
        for (int r = 0; r < 4; ++r) {
          const int row = rowbase + wr * 64 + i * 16 + lg * 4 + r;
          O[(size_t)row * 512 + jl] = (f16_t)(acc[i][j][r] + bias);
        }
    }
  } else {
    __syncthreads();
    f16_t* vtl = (f16_t*)smem;          // [128][136] f16 = 34816 B
    #pragma unroll
    for (int j = 0; j < 4; ++j) {
      const int jj = wc * 64 + j * 16 + l15;
      const float bias = bv[jb + jj];
      #pragma unroll
      for (int i = 0; i < 4; ++i)
        #pragma unroll
        for (int r = 0; r < 4; ++r) {
          const int ii = wr * 64 + i * 16 + lg * 4 + r;
          vtl[jj * 136 + ii] = (f16_t)(acc[i][j][r] + bias);
        }
    }
    __syncthreads();
    const int dv = tid >> 1, hf = tid & 1;
    const int bat = rowbase >> 11, n0 = rowbase & 2047;
    f16_t* __restrict__ dst =
        &Vt[((size_t)bat * 512 + jb + dv) * 2048 + n0 + hf * 64];
    const f16_t* src = &vtl[dv * 136 + hf * 64];
    #pragma unroll
    for (int s = 0; s < 8; ++s)
      *(f16x8*)&dst[s * 8] = *(const f16x8*)&src[s * 8];
  }
}

// ---------------------------------------------------------------------------
// S = Q K^T (fp32 out) + encoded row-max atomics.  flat grid 2048.
// decode: bat = wg>>8 (one batch per XCD), mt = (wg>>4)&15, nt = wg&15.
// ---------------------------------------------------------------------------
__global__ __launch_bounds__(256, 2) void k_qk(const f16_t* __restrict__ Q,
                                               const f16_t* __restrict__ K,
                                               float* __restrict__ S,
                                               unsigned int* __restrict__ mEnc)
{
  __shared__ __align__(16) f16_t A[128 * 64];
  __shared__ __align__(16) f16_t Bt[128 * 64];

  const int wg = xcd_swz(blockIdx.x, 2048);
  const int bat = wg >> 8, mt = (wg >> 4) & 15, nt = wg & 15;
  const int tid = threadIdx.x, lane = tid & 63, wave = tid >> 6;
  const int wr = wave >> 1, wc = wave & 1, l15 = lane & 15, lg = lane >> 4;

  f32x4 acc[4][4] = {};
  const f16_t* Abase = Q + ((size_t)bat * 2048 + mt * 128) * 512;
  const f16_t* Bbase = K + ((size_t)bat * 2048 + nt * 128) * 512;

  for (int kb = 0; kb < 512; kb += 64) {
    __syncthreads();
    stage_tile(A, Abase + kb, 512, wave, lane);
    stage_tile(Bt, Bbase + kb, 512, wave, lane);
    __syncthreads();
    #pragma unroll
    for (int h = 0; h < 2; ++h) {
      const int slot0 = h * 4 + lg;
      f16x8 af[4], bf[4];
      #pragma unroll
      for (int g = 0; g < 4; ++g) {
        af[g] = lds_frag(A, wr * 64 + g * 16 + l15, slot0);
        bf[g] = lds_frag(Bt, wc * 64 + g * 16 + l15, slot0);
      }
      #pragma unroll
      for (int i = 0; i < 4; ++i)
        #pragma unroll
        for (int j = 0; j < 4; ++j)
          acc[i][j] = mfma_h(af[i], bf[j], acc[i][j]);
    }
  }

  #pragma unroll
  for (int i = 0; i < 4; ++i)
    #pragma unroll
    for (int r = 0; r < 4; ++r) {
      const int ii = mt * 128 + wr * 64 + i * 16 + lg * 4 + r;
      float mv = fmaxf(fmaxf(acc[i][0][r], acc[i][1][r]),
                       fmaxf(acc[i][2][r], acc[i][3][r]));
      mv = fmaxf(mv, __shfl_xor(mv, 1));
      mv = fmaxf(mv, __shfl_xor(mv, 2));
      mv = fmaxf(mv, __shfl_xor(mv, 4));
      mv = fmaxf(mv, __shfl_xor(mv, 8));
      if (l15 == 0)
        atomicMax(&mEnc[(size_t)bat * 2048 + ii], fenc(mv));
      #pragma unroll
      for (int j = 0; j < 4; ++j) {
        const int jj = nt * 128 + wc * 64 + j * 16 + l15;
        S[((size_t)bat * 2048 + ii) * 2048 + jj] = acc[i][j][r];
      }
    }
}

// ---------------------------------------------------------------------------
// out = (exp(S - m) @ V) * sqrt(512)/l.  flat grid 512 = bat(8, =XCD) x
// qt(32 tiles of 64 q) x dvh(2 halves of 256 dv).  4 waves, each 64q x 64dv.
// V: global->register fragments (disjoint per wave, L2-local).
// P: exp(S-m) -> f16, double-buffered LDS, ONE lgkm-only barrier per iter.
// S: register-prefetched one iteration ahead.
// ---------------------------------------------------------------------------
__global__ __launch_bounds__(256, 2) void k_pv4(const float* __restrict__ S,
                                                const f16_t* __restrict__ Vt,
                                                const unsigned int* __restrict__ mEnc,
                                                float* __restrict__ out)
{
  __shared__ __align__(16) f16_t P[2][64 * 64];   // dbuf, 8 KB each
  __shared__ float lred[64][4];

  const int id = blockIdx.x;
  const int bat = id & 7, qt = (id >> 3) & 31, dvh = id >> 8;
  const int tid = threadIdx.x, lane = tid & 63, wave = tid >> 6;
  const int l15 = lane & 15, lg = lane >> 4;

  const int qs = tid >> 2;           // staging q row 0..63
  const int cq = tid & 3;            // quarter of the 64-kv step
  const float LOG2E = 1.4426950408889634f;
  const float mls = fdec(mEnc[bat * 2048 + qt * 64 + qs]) * LOG2E;
  const float* __restrict__ srow =
      S + ((size_t)bat * 2048 + qt * 64 + qs) * 2048 + cq * 16;

  // this wave's V fragment row pointers (dv = dvh*256 + wave*64 + j*16 + l15)
  const size_t vdv = (size_t)bat * 512 + dvh * 256 + wave * 64 + l15;
  const f16_t* __restrict__ vb0 = Vt + (vdv +  0) * 2048;
  const f16_t* __restrict__ vb1 = Vt + (vdv + 16) * 2048;
  const f16_t* __restrict__ vb2 = Vt + (vdv + 32) * 2048;
  const f16_t* __restrict__ vb3 = Vt + (vdv + 48) * 2048;

  f32x4 acc[4][4] = {};
  float l_part = 0.f;

  // ---- prologue: S_0 -> exp -> P[0]; issue S_1 ----
  float4 p0 = *(const float4*)&srow[0];
  float4 p1 = *(const float4*)&srow[4];
  float4 p2 = *(const float4*)&srow[8];
  float4 p3 = *(const float4*)&srow[12];
  float4 s0 = *(const float4*)&srow[64];
  float4 s1 = *(const float4*)&srow[64 + 4];
  float4 s2 = *(const float4*)&srow[64 + 8];
  float4 s3 = *(const float4*)&srow[64 + 12];
  {
    float e[16] = {p0.x, p0.y, p0.z, p0.w, p1.x, p1.y, p1.z, p1.w,
                   p2.x, p2.y, p2.z, p2.w, p3.x, p3.y, p3.z, p3.w};
    #pragma unroll
    for (int g2 = 0; g2 < 2; ++g2) {
      f16x8 p;
      #pragma unroll
      for (int j = 0; j < 8; ++j) {
        const float ev =
            __builtin_amdgcn_exp2f(fmaf(e[g2 * 8 + j], LOG2E, -mls));
        l_part += ev;
        p[j] = (f16_t)ev;
      }
      const int slot = cq * 2 + g2;
      *(f16x8*)&P[0][qs * 64 + ((slot ^ (qs & 7)) << 3)] = p;
    }
  }

  for (int t = 0; t < 32; ++t) {
    const int kb = t * 64;
    // single barrier: P[(t)&1] writes from iter t-1 (or prologue) visible;
    // all waves done reading P[(t-1)&1].
    asm volatile("s_waitcnt lgkmcnt(0)\n\ts_barrier" ::: "memory");
    __builtin_amdgcn_sched_barrier(0);

    // V fragments for this iter (global->reg, L2-local; hidden under exp)
    f16x8 v00, v01, v10, v11, v20, v21, v30, v31;
    {
      const int c0 = kb + lg * 8, c1 = kb + (4 + lg) * 8;
      v00 = *(const f16x8*)&vb0[c0];  v01 = *(const f16x8*)&vb0[c1];
      v10 = *(const f16x8*)&vb1[c0];  v11 = *(const f16x8*)&vb1[c1];
      v20 = *(const f16x8*)&vb2[c0];  v21 = *(const f16x8*)&vb2[c1];
      v30 = *(const f16x8*)&vb3[c0];  v31 = *(const f16x8*)&vb3[c1];
    }

    if (t < 31) {
      // consume S_{t+1} regs, reissue for S_{t+2} (wrapped, never consumed
      // when garbage), exp -> P[(t+1)&1]
      float e[16] = {s0.x, s0.y, s0.z, s0.w, s1.x, s1.y, s1.z, s1.w,
                     s2.x, s2.y, s2.z, s2.w, s3.x, s3.y, s3.z, s3.w};
      const int kn = ((t + 2) * 64) & 2047;
      s0 = *(const float4*)&srow[kn];
      s1 = *(const float4*)&srow[kn + 4];
      s2 = *(const float4*)&srow[kn + 8];
      s3 = *(const float4*)&srow[kn + 12];
      f16_t* Pn = P[(t + 1) & 1];
      #pragma unroll
      for (int g2 = 0; g2 < 2; ++g2) {
        f16x8 p;
        #pragma unroll
        for (int j = 0; j < 8; ++j) {
          const float ev =
              __builtin_amdgcn_exp2f(fmaf(e[g2 * 8 + j], LOG2E, -mls));
          l_part += ev;
          p[j] = (f16_t)ev;
        }
        const int slot = cq * 2 + g2;
        *(f16x8*)&Pn[qs * 64 + ((slot ^ (qs & 7)) << 3)] = p;
      }
    }

    // MFMA on P[t&1] (written before this iter's barrier) + V regs
    const f16_t* Pc = P[t & 1];
    #pragma unroll
    for (int ks = 0; ks < 2; ++ks) {
      const int slot0 = ks * 4 + lg;
      f16x8 af[4];
      #pragma unroll
      for (int g = 0; g < 4; ++g)
        af[g] = lds_frag(Pc, g * 16 + l15, slot0);
      const f16x8 b0 = ks ? v01 : v00;
      const f16x8 b1 = ks ? v11 : v10;
      const f16x8 b2 = ks ? v21 : v20;
      const f16x8 b3 = ks ? v31 : v30;
      #pragma unroll
      for (int i = 0; i < 4; ++i) {
        acc[i][0] = mfma_h(af[i], b0, acc[i][0]);
        acc[i][1] = mfma_h(af[i], b1, acc[i][1]);
        acc[i][2] = mfma_h(af[i], b2, acc[i][2]);
        acc[i][3] = mfma_h(af[i], b3, acc[i][3]);
      }
    }
  }

  __syncthreads();
  lred[qs][cq] = l_part;
  __syncthreads();

  #pragma unroll
  for (int i = 0; i < 4; ++i)
    #pragma unroll
    for (int r = 0; r < 4; ++r) {
      const int ql = i * 16 + lg * 4 + r;
      const float l = lred[ql][0] + lred[ql][1] + lred[ql][2] + lred[ql][3];
      const float sc = 22.62741699796952f / l;   // sqrt(512)/l
      const size_t orow = ((size_t)bat * 2048 + qt * 64 + ql) * 512;
      #pragma unroll
      for (int j = 0; j < 4; ++j) {
        const int dv = dvh * 256 + wave * 64 + j * 16 + l15;
        out[orow + dv] = acc[i][j][r] * sc;
      }
    }
}

// ---------------------------------------------------------------------------
extern "C" void kernel_launch(void* const* d_in, const int* in_sizes, int n_in,
                              void* d_out, int out_size, void* d_ws, size_t ws_size,
                              hipStream_t stream) {
  const float* x  = (const float*)d_in[0];
  const float* Wq = (const float*)d_in[1];
  const float* bq = (const float*)d_in[2];
  const float* Wk = (const float*)d_in[3];
  const float* bk = (const float*)d_in[4];
  const float* Wv = (const float*)d_in[5];
  const float* bv = (const float*)d_in[6];
  float* out = (float*)d_out;

  char* ws = (char*)d_ws;
  f16_t* x16 = (f16_t*)(ws + 0);
  f16_t* Q   = (f16_t*)(ws + 16777216);
  f16_t* K   = (f16_t*)(ws + 33554432);
  f16_t* Vt  = (f16_t*)(ws + 50331648);
  float* S   = (float*)(ws + 67108864);
  f16_t* Wt  = (f16_t*)(ws + 201326592);
  unsigned int* mEnc = (unsigned int*)(ws + 202899456);

  (void)hipMemsetAsync(mEnc, 0, 65536, stream);  // encoded -inf sentinel
  k_conv_x<<<4096, 256, 0, stream>>>(x, x16);
  k_conv_w<<<dim3(8, 8, 3), 256, 0, stream>>>(Wq, Wk, Wv, Wt);
  k_proj<<<1536, 256, 0, stream>>>(x16, Wt, bq, bk, bv, Q, K, Vt);
  k_qk<<<2048, 256, 0, stream>>>(Q, K, S, mEnc);
  k_pv4<<<512, 256, 0, stream>>>(S, Vt, mEnc, out);
}

// Round 8
// 159.019 us; speedup vs baseline: 1.1828x; 1.1828x over previous
//
#include <hip/hip_runtime.h>
#include <stdint.h>
#include <stddef.h>

// ---------------------------------------------------------------------------
// out = softmax(x Wq+bq @ (x Wk+bk)^T) * sqrt(512) @ (x Wv+bv)
// B=8, N=2048, D=DK=DV=512, fp32 I/O.
// Round 8: tile-local softmax split.
//   k_qk2: S stays in registers; epilogue computes per-row tile max m_t and
//     sum l_t, writes P_t = exp(S - m_t) as f16 (row-major, via LDS for
//     coalesced stores) + m_t, l_t arrays. No fp32 S, no atomics.
//   k_pv5: pure GEMM structure (qk clone): P staged via global_load_lds,
//     cross-tile factor f_t = exp(m_t - M) applied as per-row f16 splat mul
//     on A-fragments; denominator assembled in prologue.
// ws layout (B): x16 0, Q 16777216, K 33554432, Vt 50331648,
//   P 67108864 (67108864), mG 134217728 (2097152), lG 136314880 (2097152),
//   Wt 201326592 (1572864).  total <= 202899456.
// ---------------------------------------------------------------------------

typedef _Float16 f16_t;
typedef _Float16 f16x8 __attribute__((ext_vector_type(8)));
typedef float    f32x4 __attribute__((ext_vector_type(4)));

__device__ __forceinline__ f32x4 mfma_h(f16x8 a, f16x8 b, f32x4 c) {
  // D frag: col = lane&15, row = (lane>>4)*4 + reg
  return __builtin_amdgcn_mfma_f32_16x16x32_f16(a, b, c, 0, 0, 0);
}

__device__ __forceinline__ void gl_lds16(const void* g, void* lds) {
  __builtin_amdgcn_global_load_lds(
      (const __attribute__((address_space(1))) unsigned int*)g,
      (__attribute__((address_space(3))) unsigned int*)lds, 16, 0, 0);
}

// Stage a [128][64] f16 tile (16 KB) from row-major global via global_load_lds.
// Linear LDS dest; source pre-swizzled: phys slot s of row r holds logical
// slot s^(r&7) (16B slots, 8 per 128B row).  4-wave cooperative.
__device__ __forceinline__ void stage_tile(f16_t* lds, const f16_t* g,
                                           size_t gstride, int wave, int lane) {
  const int l8 = lane >> 3;
  const int lslot = (lane & 7) ^ l8;
  #pragma unroll
  for (int c = 0; c < 4; ++c) {
    const int chunk = wave * 4 + c;
    const int row = chunk * 8 + l8;
    gl_lds16(g + (size_t)row * gstride + lslot * 8, lds + chunk * 512);
  }
}

// Stage a [64][64] f16 tile (8 KB): 8 chunks, 2 per wave.
__device__ __forceinline__ void stage_tile64(f16_t* lds, const f16_t* g,
                                             size_t gstride, int wave, int lane) {
  const int l8 = lane >> 3;
  const int lslot = (lane & 7) ^ l8;
  #pragma unroll
  for (int c = 0; c < 2; ++c) {
    const int chunk = wave * 2 + c;
    const int row = chunk * 8 + l8;
    gl_lds16(g + (size_t)row * gstride + lslot * 8, lds + chunk * 512);
  }
}

// Swizzled fragment read: logical (row R, 8 elems at col slot*8)
__device__ __forceinline__ f16x8 lds_frag(const f16_t* buf, int R, int slot) {
  return *(const f16x8*)&buf[R * 64 + (((slot ^ (R & 7)) & 7) << 3)];
}

// XCD-chunked work remap (requires nwg % 8 == 0)
__device__ __forceinline__ int xcd_swz(int id, int nwg) {
  return (id & 7) * (nwg >> 3) + (id >> 3);
}

// ---------------------------------------------------------------------------
__global__ __launch_bounds__(256) void k_conv_x(const float* __restrict__ x,
                                                f16_t* __restrict__ x16) {
  const int i = (blockIdx.x * 256 + threadIdx.x) * 8;
  const float4 a = *(const float4*)&x[i];
  const float4 b = *(const float4*)&x[i + 4];
  float v[8] = {a.x, a.y, a.z, a.w, b.x, b.y, b.z, b.w};
  f16x8 h;
  #pragma unroll
  for (int j = 0; j < 8; ++j) h[j] = (f16_t)v[j];
  *(f16x8*)&x16[i] = h;
}

// transpose+convert W -> Wt[p][n][k] f16
__global__ __launch_bounds__(256) void k_conv_w(const float* __restrict__ Wq,
                                                const float* __restrict__ Wk,
                                                const float* __restrict__ Wv,
                                                f16_t* __restrict__ Wt) {
  __shared__ float t[64][65];
  const int p = blockIdx.z;
  const float* __restrict__ W = (p == 0) ? Wq : (p == 1) ? Wk : Wv;
  const int n0 = blockIdx.x * 64, k0 = blockIdx.y * 64;
  const int tx = threadIdx.x & 63, ty = threadIdx.x >> 6;
  #pragma unroll
  for (int j = 0; j < 16; ++j)
    t[ty * 16 + j][tx] = W[(size_t)(k0 + ty * 16 + j) * 512 + n0 + tx];
  __syncthreads();
  #pragma unroll
  for (int j = 0; j < 16; ++j) {
    const int nl = ty * 16 + j;
    Wt[(size_t)p * 262144 + (size_t)(n0 + nl) * 512 + k0 + tx] =
        (f16_t)t[tx][nl];
  }
}

// ---------------------------------------------------------------------------
// Projection: flat grid 1536 (xcd-swizzled -> mt*12+jt).  Single fp16 MFMA.
// panels 0-3 Q, 4-7 K, 8-11 V (V transposed to Vt[b][dv][n]).
// ---------------------------------------------------------------------------
__global__ __launch_bounds__(256, 2) void k_proj(
    const f16_t* __restrict__ x16, const f16_t* __restrict__ Wt,
    const float* __restrict__ bq, const float* __restrict__ bk,
    const float* __restrict__ bv,
    f16_t* __restrict__ Q, f16_t* __restrict__ K, f16_t* __restrict__ Vt)
{
  __shared__ __align__(16) unsigned char smem[34816];  // A,B tiles / vtl
  f16_t* A = (f16_t*)smem;
  f16_t* B = (f16_t*)(smem + 16384);

  const int wg = xcd_swz(blockIdx.x, 1536);
  const int mt = wg / 12, jt = wg % 12;
  const int which = jt >> 2;            // 0=Q 1=K 2=V
  const int jb = (jt & 3) * 128;

  const int tid = threadIdx.x, lane = tid & 63, wave = tid >> 6;
  const int wr = wave >> 1, wc = wave & 1, l15 = lane & 15, lg = lane >> 4;
  const int rowbase = mt * 128;

  const f16_t* Wbase = Wt + (size_t)which * 262144 + (size_t)jb * 512;

  f32x4 acc[4][4] = {};

  for (int kb = 0; kb < 512; kb += 64) {
    __syncthreads();
    stage_tile(A, x16 + (size_t)rowbase * 512 + kb, 512, wave, lane);
    stage_tile(B, Wbase + kb, 512, wave, lane);
    __syncthreads();
    #pragma unroll
    for (int h = 0; h < 2; ++h) {
      const int slot0 = h * 4 + lg;
      f16x8 af[4], bf[4];
      #pragma unroll
      for (int g = 0; g < 4; ++g) {
        af[g] = lds_frag(A, wr * 64 + g * 16 + l15, slot0);
        bf[g] = lds_frag(B, wc * 64 + g * 16 + l15, slot0);
      }
      #pragma unroll
      for (int i = 0; i < 4; ++i)
        #pragma unroll
        for (int j = 0; j < 4; ++j)
          acc[i][j] = mfma_h(af[i], bf[j], acc[i][j]);
    }
  }

  if (which != 2) {
    f16_t* __restrict__ O = (which == 0) ? Q : K;
    const float* __restrict__ bb = (which == 0) ? bq : bk;
    #pragma unroll
    for (int j = 0; j < 4; ++j) {
      const int jl = jb + wc * 64 + j * 16 + l15;
      const float bias = bb[jl];
      #pragma unroll
      for (int i = 0; i < 4; ++i)
        #pragma unroll
        for (int r = 0; r < 4; ++r) {
          const int row = rowbase + wr * 64 + i * 16 + lg * 4 + r;
          O[(size_t)row * 512 + jl] = (f16_t)(acc[i][j][r] + bias);
        }
    }
  } else {
    __syncthreads();
    f16_t* vtl = (f16_t*)smem;          // [128][136] f16 = 34816 B
    #pragma unroll
    for (int j = 0; j < 4; ++j) {
      const int jj = wc * 64 + j * 16 + l15;
      const float bias = bv[jb + jj];
      #pragma unroll
      for (int i = 0; i < 4; ++i)
        #pragma unroll
        for (int r = 0; r < 4; ++r) {
          const int ii = wr * 64 + i * 16 + lg * 4 + r;
          vtl[jj * 136 + ii] = (f16_t)(acc[i][j][r] + bias);
        }
    }
    __syncthreads();
    const int dv = tid >> 1, hf = tid & 1;
    const int bat = rowbase >> 11, n0 = rowbase & 2047;
    f16_t* __restrict__ dst =
        &Vt[((size_t)bat * 512 + jb + dv) * 2048 + n0 + hf * 64];
    const f16_t* src = &vtl[dv * 136 + hf * 64];
    #pragma unroll
    for (int s = 0; s < 8; ++s)
      *(f16x8*)&dst[s * 8] = *(const f16x8*)&src[s * 8];
  }
}

// ---------------------------------------------------------------------------
// k_qk2: P_t = exp(QK^T - m_t) f16 per 128-col tile + m_t, l_t arrays.
// flat grid 2048: bat = wg>>8 (one batch per XCD), mt=(wg>>4)&15, nt=wg&15.
// mG/lG layout: [(bat*16 + nt)*2048 + q_row].
// ---------------------------------------------------------------------------
__global__ __launch_bounds__(256, 2) void k_qk2(const f16_t* __restrict__ Q,
                                                const f16_t* __restrict__ K,
                                                f16_t* __restrict__ P,
                                                float* __restrict__ mG,
                                                float* __restrict__ lG)
{
  __shared__ __align__(16) unsigned char smem[34816];  // A+Bt staging / Pl
  f16_t* A  = (f16_t*)smem;
  f16_t* Bt = (f16_t*)(smem + 16384);
  __shared__ float redm[128][2];
  __shared__ float redl[128][2];

  const int wg = xcd_swz(blockIdx.x, 2048);
  const int bat = wg >> 8, mt = (wg >> 4) & 15, nt = wg & 15;
  const int tid = threadIdx.x, lane = tid & 63, wave = tid >> 6;
  const int wr = wave >> 1, wc = wave & 1, l15 = lane & 15, lg = lane >> 4;

  f32x4 acc[4][4] = {};
  const f16_t* Abase = Q + ((size_t)bat * 2048 + mt * 128) * 512;
  const f16_t* Bbase = K + ((size_t)bat * 2048 + nt * 128) * 512;

  for (int kb = 0; kb < 512; kb += 64) {
    __syncthreads();
    stage_tile(A, Abase + kb, 512, wave, lane);
    stage_tile(Bt, Bbase + kb, 512, wave, lane);
    __syncthreads();
    #pragma unroll
    for (int h = 0; h < 2; ++h) {
      const int slot0 = h * 4 + lg;
      f16x8 af[4], bf[4];
      #pragma unroll
      for (int g = 0; g < 4; ++g) {
        af[g] = lds_frag(A, wr * 64 + g * 16 + l15, slot0);
        bf[g] = lds_frag(Bt, wc * 64 + g * 16 + l15, slot0);
      }
      #pragma unroll
      for (int i = 0; i < 4; ++i)
        #pragma unroll
        for (int j = 0; j < 4; ++j)
          acc[i][j] = mfma_h(af[i], bf[j], acc[i][j]);
    }
  }

  // ---- epilogue: per-row tile max (this wave's 64 cols -> combine halves) ----
  const float LOG2E = 1.4426950408889634f;
  #pragma unroll
  for (int i = 0; i < 4; ++i)
    #pragma unroll
    for (int r = 0; r < 4; ++r) {
      float mv = fmaxf(fmaxf(acc[i][0][r], acc[i][1][r]),
                       fmaxf(acc[i][2][r], acc[i][3][r]));
      mv = fmaxf(mv, __shfl_xor(mv, 1));
      mv = fmaxf(mv, __shfl_xor(mv, 2));
      mv = fmaxf(mv, __shfl_xor(mv, 4));
      mv = fmaxf(mv, __shfl_xor(mv, 8));
      if (l15 == 0) redm[wr * 64 + i * 16 + lg * 4 + r][wc] = mv;
    }
  __syncthreads();   // also fences A/Bt reads before Pl overlay

  f16_t* Pl = (f16_t*)smem;   // [128][136]
  #pragma unroll
  for (int i = 0; i < 4; ++i)
    #pragma unroll
    for (int r = 0; r < 4; ++r) {
      const int rl = wr * 64 + i * 16 + lg * 4 + r;
      const float m = fmaxf(redm[rl][0], redm[rl][1]);
      float sum = 0.f;
      #pragma unroll
      for (int j = 0; j < 4; ++j) {
        const float e =
            __builtin_amdgcn_exp2f((acc[i][j][r] - m) * LOG2E);
        const f16_t h = (f16_t)e;
        Pl[rl * 136 + wc * 64 + j * 16 + l15] = h;
        sum += (float)h;
      }
      sum += __shfl_xor(sum, 1);
      sum += __shfl_xor(sum, 2);
      sum += __shfl_xor(sum, 4);
      sum += __shfl_xor(sum, 8);
      if (l15 == 0) redl[rl][wc] = sum;
    }
  __syncthreads();

  // m_t / l_t stores (one lane per row)
  if (wc == 0 && l15 == 0) {
    #pragma unroll
    for (int i = 0; i < 4; ++i)
      #pragma unroll
      for (int r = 0; r < 4; ++r) {
        const int rl = wr * 64 + i * 16 + lg * 4 + r;
        const size_t idx =
            ((size_t)(bat * 16 + nt)) * 2048 + mt * 128 + rl;
        mG[idx] = fmaxf(redm[rl][0], redm[rl][1]);
        lG[idx] = redl[rl][0] + redl[rl][1];
      }
  }

  // coalesced P store-out: 2 threads per row, 64 f16 each
  {
    const int row = tid >> 1, half = tid & 1;
    f16_t* __restrict__ dst =
        P + ((size_t)bat * 2048 + mt * 128 + row) * 2048 + nt * 128 + half * 64;
    const f16_t* src = &Pl[row * 136 + half * 64];
    #pragma unroll
    for (int s = 0; s < 8; ++s)
      *(f16x8*)&dst[s * 8] = *(const f16x8*)&src[s * 8];
  }
}

// ---------------------------------------------------------------------------
// k_pv5: out = (sum_t P_t f_t @ V) * sqrt(512)/l,  f_t = exp(m_t - M).
// flat grid 512 = bat(8,=XCD) x qt(32 x 64q) x dvh(2 x 256dv). 4 waves,
// each 64q x 64dv.  P staged via gl_lds; f_t applied on A-fragments.
// ---------------------------------------------------------------------------
__global__ __launch_bounds__(256, 2) void k_pv5(const f16_t* __restrict__ P,
                                                const f16_t* __restrict__ Vt,
                                                const float* __restrict__ mG,
                                                const float* __restrict__ lG,
                                                float* __restrict__ out)
{
  __shared__ __align__(16) f16_t Pl[64 * 64];     // 8 KB
  __shared__ __align__(16) f16_t Vl[256 * 64];    // 32 KB
  __shared__ f16_t facL[64][16];                  // 2 KB
  __shared__ float scrow[64];
  __shared__ float redp[64][4];

  const int id = blockIdx.x;
  const int bat = id & 7, qt = (id >> 3) & 31, dvh = id >> 8;
  const int tid = threadIdx.x, lane = tid & 63, wave = tid >> 6;
  const int l15 = lane & 15, lg = lane >> 4;
  const float LOG2E = 1.4426950408889634f;

  // ---- prologue: M = max_t m_t, facL[row][t] = exp(m_t - M),
  //      scrow[row] = sqrt(512) / sum_t l_t*f_t ----
  {
    const int prow = tid >> 2, part = tid & 3;
    float mt4[4], lt4[4];
    #pragma unroll
    for (int s = 0; s < 4; ++s) {
      const size_t idx =
          ((size_t)(bat * 16 + part * 4 + s)) * 2048 + qt * 64 + prow;
      mt4[s] = mG[idx];
      lt4[s] = lG[idx];
    }
    float mm = fmaxf(fmaxf(mt4[0], mt4[1]), fmaxf(mt4[2], mt4[3]));
    redp[prow][part] = mm;
    __syncthreads();
    const float M = fmaxf(fmaxf(redp[prow][0], redp[prow][1]),
                          fmaxf(redp[prow][2], redp[prow][3]));
    __syncthreads();
    float ls = 0.f;
    #pragma unroll
    for (int s = 0; s < 4; ++s) {
      const float f = __builtin_amdgcn_exp2f((mt4[s] - M) * LOG2E);
      facL[prow][part * 4 + s] = (f16_t)f;
      ls += lt4[s] * f;
    }
    redp[prow][part] = ls;
    __syncthreads();
    if (part == 0)
      scrow[prow] = 22.62741699796952f /
                    (redp[prow][0] + redp[prow][1] + redp[prow][2] + redp[prow][3]);
  }

  const f16_t* Pbase = P + ((size_t)bat * 2048 + qt * 64) * 2048;
  const f16_t* Vbase = Vt + ((size_t)bat * 512 + dvh * 256) * 2048;

  f32x4 acc[4][4] = {};

  for (int tt = 0; tt < 16; ++tt) {
    // per-row factors for this 128-col tile (rows g*16+l15)
    f16_t fv[4];
    #pragma unroll
    for (int g = 0; g < 4; ++g) fv[g] = facL[g * 16 + l15][tt];

    #pragma unroll
    for (int h2 = 0; h2 < 2; ++h2) {
      const int kb = tt * 128 + h2 * 64;
      __syncthreads();
      stage_tile(Vl, Vbase + kb, 2048, wave, lane);
      stage_tile(Vl + 128 * 64, Vbase + (size_t)128 * 2048 + kb, 2048, wave, lane);
      stage_tile64(Pl, Pbase + kb, 2048, wave, lane);
      __syncthreads();
      #pragma unroll
      for (int ks = 0; ks < 2; ++ks) {
        const int slot0 = ks * 4 + lg;
        f16x8 af[4], bf[4];
        #pragma unroll
        for (int g = 0; g < 4; ++g) {
          af[g] = lds_frag(Pl, g * 16 + l15, slot0) * fv[g];
          bf[g] = lds_frag(Vl, wave * 64 + g * 16 + l15, slot0);
        }
        #pragma unroll
        for (int i = 0; i < 4; ++i)
          #pragma unroll
          for (int j = 0; j < 4; ++j)
            acc[i][j] = mfma_h(af[i], bf[j], acc[i][j]);
      }
    }
  }

  #pragma unroll
  for (int i = 0; i < 4; ++i)
    #pragma unroll
    for (int r = 0; r < 4; ++r) {
      const int ql = i * 16 + lg * 4 + r;
      const float sc = scrow[ql];
      const size_t orow = ((size_t)bat * 2048 + qt * 64 + ql) * 512;
      #pragma unroll
      for (int j = 0; j < 4; ++j) {
        const int dv = dvh * 256 + wave * 64 + j * 16 + l15;
        out[orow + dv] = acc[i][j][r] * sc;
      }
    }
}

// ---------------------------------------------------------------------------
extern "C" void kernel_launch(void* const* d_in, const int* in_sizes, int n_in,
                              void* d_out, int out_size, void* d_ws, size_t ws_size,
                              hipStream_t stream) {
  const float* x  = (const float*)d_in[0];
  const float* Wq = (const float*)d_in[1];
  const float* bq = (const float*)d_in[2];
  const float* Wk = (const float*)d_in[3];
  const float* bk = (const float*)d_in[4];
  const float* Wv = (const float*)d_in[5];
  const float* bv = (const float*)d_in[6];
  float* out = (float*)d_out;

  char* ws = (char*)d_ws;
  f16_t* x16 = (f16_t*)(ws + 0);
  f16_t* Q   = (f16_t*)(ws + 16777216);
  f16_t* K   = (f16_t*)(ws + 33554432);
  f16_t* Vt  = (f16_t*)(ws + 50331648);
  f16_t* P   = (f16_t*)(ws + 67108864);
  float* mG  = (float*)(ws + 134217728);
  float* lG  = (float*)(ws + 136314880);
  f16_t* Wt  = (f16_t*)(ws + 201326592);

  k_conv_x<<<4096, 256, 0, stream>>>(x, x16);
  k_conv_w<<<dim3(8, 8, 3), 256, 0, stream>>>(Wq, Wk, Wv, Wt);
  k_proj<<<1536, 256, 0, stream>>>(x16, Wt, bq, bk, bv, Q, K, Vt);
  k_qk2<<<2048, 256, 0, stream>>>(Q, K, P, mG, lG);
  k_pv5<<<512, 256, 0, stream>>>(P, Vt, mG, lG, out);
}